// Round 4
// baseline (3018.048 us; speedup 1.0000x reference)
//
#include <hip/hip_runtime.h>
#include <stdint.h>
#include <stddef.h>

#define BATCH 4096
#define HID   1024
#define EMB   64
#define KDIM  1088
#define NSTEP 19
#define NOBS  8

#define TPB   256
#define NBLK  512
#define BUFH  12288   // halfs per LDS buffer: A 128x32 (4096) + B 256x32 (8192)

typedef _Float16 f16;
typedef _Float16 half8 __attribute__((ext_vector_type(8)));
typedef float    float4v __attribute__((ext_vector_type(4)));

__device__ __forceinline__ float sigm(float x) { return 1.f / (1.f + __expf(-x)); }
__device__ __forceinline__ float tanh_f(float x) { return 1.f - 2.f / (__expf(2.f * x) + 1.f); }

__device__ __forceinline__ void gload_lds16(const void* gp, void* lp) {
  __builtin_amdgcn_global_load_lds(
      (const __attribute__((address_space(1))) uint32_t*)gp,
      (__attribute__((address_space(3))) uint32_t*)lp, 16, 0, 0);
}

// Hand-rolled barriers: vmcnt(6) keeps the newest stage batch (6 loads/wave)
// in flight across the barrier; vmcnt(0) drains fully (pipeline tail).
#define BAR6() asm volatile("s_waitcnt vmcnt(6)\n\ts_barrier" ::: "memory")
#define BAR0() asm volatile("s_waitcnt vmcnt(0)\n\ts_barrier" ::: "memory")

// ---------------------------------------------------------------------------
// Software grid barrier: relaxed spin + one fence each side.
// ---------------------------------------------------------------------------
__device__ __forceinline__ void gbar(unsigned* cnt, unsigned* gen) {
  __syncthreads();
  if (threadIdx.x == 0) {
    __threadfence();
    unsigned g = __hip_atomic_load(gen, __ATOMIC_RELAXED, __HIP_MEMORY_SCOPE_AGENT);
    __hip_atomic_fetch_add(cnt, 1u, __ATOMIC_RELAXED, __HIP_MEMORY_SCOPE_AGENT);
    if (__hip_atomic_load(cnt, __ATOMIC_RELAXED, __HIP_MEMORY_SCOPE_AGENT) == 0) {}
    // re-read not needed; decide on the fetch_add result instead:
    // (kept simple: last arriver flips gen)
    // NOTE: fetch_add returns old value; recompute:
    __threadfence();
  }
  __syncthreads();
}

// proper version (used below)
__device__ __forceinline__ void grid_barrier(unsigned* cnt, unsigned* gen) {
  __syncthreads();
  if (threadIdx.x == 0) {
    __threadfence();
    unsigned g = __hip_atomic_load(gen, __ATOMIC_RELAXED, __HIP_MEMORY_SCOPE_AGENT);
    unsigned old = __hip_atomic_fetch_add(cnt, 1u, __ATOMIC_RELAXED, __HIP_MEMORY_SCOPE_AGENT);
    if (old == NBLK - 1) {
      __hip_atomic_store(cnt, 0u, __ATOMIC_RELAXED, __HIP_MEMORY_SCOPE_AGENT);
      __hip_atomic_store(gen, g + 1u, __ATOMIC_RELAXED, __HIP_MEMORY_SCOPE_AGENT);
    } else {
      unsigned spins = 0;
      while (__hip_atomic_load(gen, __ATOMIC_RELAXED, __HIP_MEMORY_SCOPE_AGENT) == g) {
        __builtin_amdgcn_s_sleep(4);
        if (++spins > 60000000u) break;  // bail instead of hard hang
      }
    }
    __threadfence();
  }
  __syncthreads();
}

// ---------------------------------------------------------------------------
// Pack W_ih|W_hh -> fp16 Wc[4096][1088].
// Packed row p = 256T + 128cp + 64v + 16g + u  <->  orig gate-g row
// T*64 + cp*32 + v*16 + u  (T=bn tile of 256 packed cols = 64 h-cols).
// ---------------------------------------------------------------------------
__global__ void pack_kernel(const float* __restrict__ W_ih, const float* __restrict__ b_ih,
                            const float* __restrict__ W_hh, const float* __restrict__ b_hh,
                            f16* __restrict__ Wc, float* __restrict__ bc) {
  int gid = blockIdx.x * blockDim.x + threadIdx.x;
  int p = gid / KDIM;
  int k = gid - p * KDIM;
  int T = p >> 8;
  int cp = (p >> 7) & 1;
  int v = (p >> 6) & 1;
  int g = (p >> 4) & 3;
  int u = p & 15;
  int orig = g * HID + T * 64 + cp * 32 + v * 16 + u;
  float val = (k < EMB) ? W_ih[orig * EMB + k] : W_hh[orig * HID + (k - EMB)];
  Wc[gid] = (f16)val;
  if (k == 0) bc[p] = b_ih[orig] + b_hh[orig];
}

// ---------------------------------------------------------------------------
// Stage A (128 rows x 32 halfs) + B (256 rows x 32 halfs) into one buffer.
// Exactly 6 global_load_lds per thread (A:2, B:4). XOR-swizzled 16B chunks.
// ---------------------------------------------------------------------------
__device__ __forceinline__ void stage(const f16* __restrict__ X, const f16* __restrict__ Wc,
                                      f16* __restrict__ buf, int k0,
                                      int bm, int bn, int tid, int w) {
  char* base = (char*)buf;
#pragma unroll
  for (int h = 0; h < 2; ++h) {
    int s = tid + 256 * h;
    int r = s >> 2, cl = (s & 3) ^ ((r >> 1) & 3);
    gload_lds16((const char*)(X + (size_t)(bm * 128 + r) * KDIM + k0) + cl * 16,
                base + (256 * h + 64 * w) * 16);
  }
#pragma unroll
  for (int h = 0; h < 4; ++h) {
    int s = tid + 256 * h;
    int r = s >> 2, cl = (s & 3) ^ ((r >> 1) & 3);
    gload_lds16((const char*)(Wc + (size_t)(bn * 256 + r) * KDIM + k0) + cl * 16,
                base + 8192 + (256 * h + 64 * w) * 16);
  }
}

// compute one 32x256 wave-tile K-step from a staged buffer
__device__ __forceinline__ void compute(const f16* __restrict__ buf, int aw, int bofs,
                                        float4v acc[2][16]) {
  half8 af0 = *(const half8*)(buf + aw);
  half8 af1 = *(const half8*)(buf + aw + 512);
#pragma unroll
  for (int g4 = 0; g4 < 4; ++g4) {
    half8 bf[4];
#pragma unroll
    for (int i = 0; i < 4; ++i) bf[i] = *(const half8*)(buf + bofs + (g4 * 4 + i) * 512);
#pragma unroll
    for (int i = 0; i < 4; ++i) {
      acc[0][g4 * 4 + i] = __builtin_amdgcn_mfma_f32_16x16x32_f16(af0, bf[i], acc[0][g4 * 4 + i], 0, 0, 0);
      acc[1][g4 * 4 + i] = __builtin_amdgcn_mfma_f32_16x16x32_f16(af1, bf[i], acc[1][g4 * 4 + i], 0, 0, 0);
    }
  }
}

// out[row][0:5] for the block's 8 rows (2 per wave); also save nv to s_nv.
__device__ __forceinline__ void do_outproj(const f16* __restrict__ Xh,
                                           const float* __restrict__ W_out,
                                           const float* __restrict__ b_out,
                                           float* __restrict__ out_t,
                                           float (*s_nv)[2], int row0, int w, int lane) {
#pragma unroll
  for (int rr = 0; rr < 2; ++rr) {
    const int row = row0 + w * 2 + rr;
    const f16* hrow = Xh + (size_t)row * KDIM + EMB;
    half8 h0 = *(const half8*)(hrow + lane * 16);
    half8 h1 = *(const half8*)(hrow + lane * 16 + 8);
    float a[5];
#pragma unroll
    for (int o = 0; o < 5; ++o) {
      const float* wo = W_out + o * HID + lane * 16;
      float s = 0.f;
#pragma unroll
      for (int e = 0; e < 8; ++e) s += (float)h0[e] * wo[e];
#pragma unroll
      for (int e = 0; e < 8; ++e) s += (float)h1[e] * wo[8 + e];
      a[o] = s;
    }
#pragma unroll
    for (int sh = 32; sh > 0; sh >>= 1)
#pragma unroll
      for (int o = 0; o < 5; ++o) a[o] += __shfl_down(a[o], sh, 64);
    if (lane == 0) {
#pragma unroll
      for (int o = 0; o < 5; ++o) out_t[(size_t)row * 5 + o] = a[o] + b_out[o];
      s_nv[w * 2 + rr][0] = a[0] + b_out[0];
      s_nv[w * 2 + rr][1] = a[1] + b_out[1];
    }
  }
}

// ---------------------------------------------------------------------------
__global__ __launch_bounds__(TPB, 2)
void lstm_kernel(const float* __restrict__ observed,
                 const float* __restrict__ W_emb, const float* __restrict__ b_emb,
                 const f16* __restrict__ Wc, const float* __restrict__ bc,
                 const float* __restrict__ W_out, const float* __restrict__ b_out,
                 f16* __restrict__ X0, f16* __restrict__ X1,
                 float* __restrict__ out, unsigned* __restrict__ bar) {
  __shared__ f16 sbuf0[BUFH];
  __shared__ f16 sbuf1[BUFH];
  __shared__ f16 sbuf2[BUFH];
  __shared__ float s_nv[8][2];
  unsigned* cnt = bar;
  unsigned* gen = bar + 1;

  const int tid = threadIdx.x;
  const int lane = tid & 63;
  const int w = tid >> 6;
  const int l15 = lane & 15;
  const int quad = lane >> 4;
  const int L = blockIdx.x;
  const int bm = L >> 4;            // 0..31  (128-row strip)
  const int q = L & 15;
  const int bn = ((q & 7) << 1) | (q >> 3);  // XCD L%8 hosts bn {2x,2x+1}
  const int row0 = bm * 128 + q * 8;         // this block's 8 out/emb rows

  // loop-invariant fragment offsets (halfs): swizzle chunk depends only on
  // (l15>>1)&3 for both A and B (row strides are multiples of 4 rows).
  const int fragoff = l15 * 32 + ((quad ^ ((l15 >> 1) & 3)) * 8);
  const int aw = w * 1024 + fragoff;     // + mi*512
  const int bofs = 4096 + fragoff;       // + ni*512

  // bias per (cp,v,g) for this lane's l15
  float bq[2][2][4];
#pragma unroll
  for (int cp = 0; cp < 2; ++cp)
#pragma unroll
    for (int v = 0; v < 2; ++v)
#pragma unroll
      for (int g = 0; g < 4; ++g)
        bq[cp][v][g] = bc[bn * 256 + cp * 128 + v * 64 + g * 16 + l15];

  float c_reg[32];
#pragma unroll
  for (int i = 0; i < 32; ++i) c_reg[i] = 0.f;

  // prologue: emb(step 0) for own 8 rows into X0
#pragma unroll
  for (int s = tid; s < 512; s += TPB) {
    int rr = s >> 6, jc = s & 63;
    int row = row0 + rr;
    const float* o0 = observed + row * 2;
    const float* o1 = o0 + BATCH * 2;
    float d0 = o1[0] - o0[0], d1 = o1[1] - o0[1];
    float vv = d0 * W_emb[2 * jc] + d1 * W_emb[2 * jc + 1] + b_emb[jc];
    X0[(size_t)row * KDIM + jc] = (f16)fmaxf(vv, 0.f);
  }
  grid_barrier(cnt, gen);

  for (int t = 0; t < NSTEP; ++t) {
    const f16* Xc = (t & 1) ? X1 : X0;
    f16* Xn = (t & 1) ? X0 : X1;

    float4v acc[2][16];
#pragma unroll
    for (int mi = 0; mi < 2; ++mi)
#pragma unroll
      for (int ni = 0; ni < 16; ++ni) acc[mi][ni] = (float4v){0.f, 0.f, 0.f, 0.f};

    // pipeline prologue: stage kt=0,1; deferred obs out-proj overlaps them
    stage(Xc, Wc, sbuf0, 0, bm, bn, tid, w);
    stage(Xc, Wc, sbuf1, 32, bm, bn, tid, w);
    if (t >= 1 && t <= 7)
      do_outproj(Xc, W_out, b_out, out + (size_t)(t - 1) * BATCH * 5, s_nv, row0, w, lane);
    __syncthreads();  // compiler drains vmcnt(0): both buffers + outproj loads

    // steady state: 10 triples (kt 0..29), stages kt+2 (2..31)
    for (int i = 0; i < 10; ++i) {
      const int kb = 3 * i;
      stage(Xc, Wc, sbuf2, (kb + 2) * 32, bm, bn, tid, w);
      compute(sbuf0, aw, bofs, acc);
      BAR6();
      stage(Xc, Wc, sbuf0, (kb + 3) * 32, bm, bn, tid, w);
      compute(sbuf1, aw, bofs, acc);
      BAR6();
      stage(Xc, Wc, sbuf1, (kb + 4) * 32, bm, bn, tid, w);
      compute(sbuf2, aw, bofs, acc);
      BAR6();
    }
    // kt=30..33 tail
    stage(Xc, Wc, sbuf2, 32 * 32, bm, bn, tid, w);
    compute(sbuf0, aw, bofs, acc);   // kt=30
    BAR6();
    stage(Xc, Wc, sbuf0, 33 * 32, bm, bn, tid, w);
    compute(sbuf1, aw, bofs, acc);   // kt=31
    BAR6();
    compute(sbuf2, aw, bofs, acc);   // kt=32
    BAR0();                          // drain stage(33)
    compute(sbuf0, aw, bofs, acc);   // kt=33

    // in-register LSTM cell epilogue
#pragma unroll
    for (int mi = 0; mi < 2; ++mi) {
#pragma unroll
      for (int cp = 0; cp < 2; ++cp) {
#pragma unroll
        for (int v = 0; v < 2; ++v) {
          const int ni = cp * 8 + v * 4;
          const int jj = bn * 64 + cp * 32 + v * 16 + l15;
          const int ci = ((mi * 2 + cp) * 2 + v) * 4;
#pragma unroll
          for (int r = 0; r < 4; ++r) {
            const int row = bm * 128 + w * 32 + mi * 16 + quad * 4 + r;
            float gi = acc[mi][ni + 0][r] + bq[cp][v][0];
            float gf = acc[mi][ni + 1][r] + bq[cp][v][1];
            float gg = acc[mi][ni + 2][r] + bq[cp][v][2];
            float go = acc[mi][ni + 3][r] + bq[cp][v][3];
            float cn = sigm(gf) * c_reg[ci + r] + sigm(gi) * tanh_f(gg);
            c_reg[ci + r] = cn;
            float h = sigm(go) * tanh_f(cn);
            Xn[(size_t)row * KDIM + EMB + jj] = (f16)h;
          }
        }
      }
    }

    // next obs emb (from observed) for own 8 rows
    if (t + 1 < NOBS) {
#pragma unroll
      for (int s = tid; s < 512; s += TPB) {
        int rr = s >> 6, jc = s & 63;
        int row = row0 + rr;
        const float* o0 = observed + (size_t)(t + 1) * BATCH * 2 + row * 2;
        const float* o1 = o0 + BATCH * 2;
        float d0 = o1[0] - o0[0], d1 = o1[1] - o0[1];
        float vv = d0 * W_emb[2 * jc] + d1 * W_emb[2 * jc + 1] + b_emb[jc];
        Xn[(size_t)row * KDIM + jc] = (f16)fmaxf(vv, 0.f);
      }
    }

    grid_barrier(cnt, gen);  // h (+ obs emb) complete

    if (t >= 7) {
      do_outproj(Xn, W_out, b_out, out + (size_t)t * BATCH * 5, s_nv, row0, w, lane);
      if (t + 1 < NSTEP) {
        __syncthreads();  // s_nv visibility within block
#pragma unroll
        for (int s = tid; s < 512; s += TPB) {
          int rr = s >> 6, jc = s & 63;
          int row = row0 + rr;
          float d0 = s_nv[rr][0], d1 = s_nv[rr][1];
          float vv = d0 * W_emb[2 * jc] + d1 * W_emb[2 * jc + 1] + b_emb[jc];
          Xn[(size_t)row * KDIM + jc] = (f16)fmaxf(vv, 0.f);
        }
        grid_barrier(cnt, gen);  // pred emb complete
      }
    }
  }
}

// ---------------------------------------------------------------------------
extern "C" void kernel_launch(void* const* d_in, const int* in_sizes, int n_in,
                              void* d_out, int out_size, void* d_ws, size_t ws_size,
                              hipStream_t stream) {
  const float* observed = (const float*)d_in[0];
  const float* W_emb = (const float*)d_in[1];
  const float* b_emb = (const float*)d_in[2];
  const float* W_ih = (const float*)d_in[3];
  const float* b_ih = (const float*)d_in[4];
  const float* W_hh = (const float*)d_in[5];
  const float* b_hh = (const float*)d_in[6];
  const float* W_out = (const float*)d_in[7];
  const float* b_out = (const float*)d_in[8];
  float* out = (float*)d_out;

  uint8_t* ws = (uint8_t*)d_ws;
  const size_t WC_BYTES = (size_t)4096 * KDIM * sizeof(f16);  // 8,912,896
  f16* Wc = (f16*)ws;
  float* bc = (float*)(ws + WC_BYTES);
  f16* X0 = (f16*)(ws + WC_BYTES + 16384);
  f16* X1 = (f16*)(ws + 2 * WC_BYTES + 16384);
  unsigned* bar = (unsigned*)(ws + 3 * WC_BYTES + 16384);

  pack_kernel<<<(4096 * KDIM) / 256, 256, 0, stream>>>(W_ih, b_ih, W_hh, b_hh, Wc, bc);
  hipMemsetAsync(X0, 0, WC_BYTES, stream);  // h0 = 0 (emb cols written in-kernel)
  hipMemsetAsync(bar, 0, 128, stream);      // barrier cnt/gen = 0

  lstm_kernel<<<NBLK, TPB, 0, stream>>>(observed, W_emb, b_emb, Wc, bc,
                                        W_out, b_out, X0, X1, out, bar);
}

// Round 5
// 1296.560 us; speedup vs baseline: 2.3277x; 2.3277x over previous
//
#include <hip/hip_runtime.h>
#include <stdint.h>
#include <stddef.h>

#define BATCH 4096
#define HID   1024
#define EMB   64
#define KDIM  1088
#define NSTEP 19
#define NOBS  8

#define BM 128
#define BN 128
#define BK 32

typedef _Float16 f16;
typedef _Float16 half8 __attribute__((ext_vector_type(8)));
typedef float    float4v __attribute__((ext_vector_type(4)));

__device__ __forceinline__ float sigm(float x) { return 1.f / (1.f + __expf(-x)); }
__device__ __forceinline__ float tanh_f(float x) { return 1.f - 2.f / (__expf(2.f * x) + 1.f); }

__device__ __forceinline__ void gload_lds16(const void* gp, void* lp) {
  __builtin_amdgcn_global_load_lds(
      (const __attribute__((address_space(1))) uint32_t*)gp,
      (__attribute__((address_space(3))) uint32_t*)lp, 16, 0, 0);
}

// ---------------------------------------------------------------------------
// Pack W_ih|W_hh (fp32) -> interleaved fp16 Wc [4096][1088] + combined bias.
// Packed row p = 128*t + 32*g + u  <->  original gate row g*1024 + 32*t + u.
// (proven r1 layout: a 128-wide N-tile holds i,f,g,o for 32 h-cols)
// ---------------------------------------------------------------------------
__global__ void pack_kernel(const float* __restrict__ W_ih, const float* __restrict__ b_ih,
                            const float* __restrict__ W_hh, const float* __restrict__ b_hh,
                            f16* __restrict__ Wc, float* __restrict__ bc) {
  int gid = blockIdx.x * blockDim.x + threadIdx.x;
  int p = gid / KDIM;
  int k = gid - p * KDIM;
  int t = p >> 7;
  int g = (p >> 5) & 3;
  int u = p & 31;
  int orig = g * HID + t * 32 + u;
  float v = (k < EMB) ? W_ih[orig * EMB + k] : W_hh[orig * HID + (k - EMB)];
  Wc[gid] = (f16)v;
  if (k == 0) bc[p] = b_ih[orig] + b_hh[orig];
}

// ---------------------------------------------------------------------------
// emb(step 0) only: X[b][0:64] = fp16(relu(diffs0 @ W_emb^T + b_emb))
// ---------------------------------------------------------------------------
__global__ void emb0_kernel(const float* __restrict__ observed,
                            const float* __restrict__ W_emb, const float* __restrict__ b_emb,
                            f16* __restrict__ Xc) {
  int gid = blockIdx.x * blockDim.x + threadIdx.x;  // BATCH*EMB
  int b = gid >> 6, j = gid & 63;
  const float* o0 = observed + b * 2;
  const float* o1 = o0 + BATCH * 2;
  float d0 = o1[0] - o0[0];
  float d1 = o1[1] - o0[1];
  float v = d0 * W_emb[2 * j] + d1 * W_emb[2 * j + 1] + b_emb[j];
  Xc[(size_t)b * KDIM + j] = (f16)fmaxf(v, 0.f);
}

// ---------------------------------------------------------------------------
// Fused gates-GEMM + LSTM cell (+ fused obs-emb for step t+1 on bn==0 blocks).
// c-state: per-thread-contiguous layout, 4 coalesced float4 per thread.
// ---------------------------------------------------------------------------
__global__ __launch_bounds__(256, 4)
void gemm_cell_kernel(const f16* __restrict__ Xc, const f16* __restrict__ Wc,
                      const float* __restrict__ bc,
                      float* __restrict__ c_ws, f16* __restrict__ Xn,
                      const float* __restrict__ obs_next, int do_emb,
                      const float* __restrict__ W_emb, const float* __restrict__ b_emb) {
  __shared__ f16 smem[2 * BM * BK];  // A [0,4096), B [4096,8192)
  const int tid = threadIdx.x;
  const int lane = tid & 63;
  const int w = tid >> 6;
  const int l15 = lane & 15;
  const int quad = lane >> 4;
  const int bm = blockIdx.y, bn = blockIdx.x;

  float4v acc[2][8];
#pragma unroll
  for (int mi = 0; mi < 2; ++mi)
#pragma unroll
    for (int ni = 0; ni < 8; ++ni)
      acc[mi][ni] = (float4v){0.f, 0.f, 0.f, 0.f};

  // loop-invariant fragment offsets
  int a_off[2], b_off[8];
#pragma unroll
  for (int mi = 0; mi < 2; ++mi) {
    int r = w * 32 + mi * 16 + l15;
    a_off[mi] = r * 32 + (quad ^ ((r >> 1) & 3)) * 8;
  }
#pragma unroll
  for (int ni = 0; ni < 8; ++ni) {
    int r = ni * 16 + l15;
    b_off[ni] = BM * BK + r * 32 + (quad ^ ((r >> 1) & 3)) * 8;
  }

  for (int kt = 0; kt < KDIM / BK; ++kt) {
    const int k0 = kt * BK;
    __syncthreads();
#pragma unroll
    for (int cph = 0; cph < 2; ++cph) {
      int s = tid + cph * 256;
      int r = s >> 2;
      int cl = (s & 3) ^ ((r >> 1) & 3);
      const f16* ga = Xc + (size_t)(bm * BM + r) * KDIM + k0 + cl * 8;
      const f16* gb = Wc + (size_t)(bn * BN + r) * KDIM + k0 + cl * 8;
      uint32_t lbase = (uint32_t)(w * 64 + cph * 256) * 16;  // wave-uniform
      gload_lds16(ga, (char*)smem + lbase);
      gload_lds16(gb, (char*)smem + 8192 + lbase);
    }
    __syncthreads();

    half8 af[2];
#pragma unroll
    for (int mi = 0; mi < 2; ++mi) af[mi] = *(const half8*)(smem + a_off[mi]);
    // B fragments in 2 groups of 4 to cap live VGPRs (reg budget for 4 blk/CU)
#pragma unroll
    for (int g4 = 0; g4 < 2; ++g4) {
      half8 bf[4];
#pragma unroll
      for (int i = 0; i < 4; ++i) bf[i] = *(const half8*)(smem + b_off[g4 * 4 + i]);
#pragma unroll
      for (int mi = 0; mi < 2; ++mi)
#pragma unroll
        for (int i = 0; i < 4; ++i)
          acc[mi][g4 * 4 + i] =
              __builtin_amdgcn_mfma_f32_16x16x32_f16(af[mi], bf[i], acc[mi][g4 * 4 + i], 0, 0, 0);
    }
  }

  // ---- in-register LSTM cell epilogue, coalesced c-state ----
  float bias[8];
#pragma unroll
  for (int ni = 0; ni < 8; ++ni) bias[ni] = bc[bn * BN + ni * 16 + l15];

  float* cbase = c_ws + ((size_t)(blockIdx.y * 32 + blockIdx.x) * 256 + tid) * 16;
  float4v cv[4];
#pragma unroll
  for (int q = 0; q < 4; ++q) cv[q] = *(const float4v*)(cbase + q * 4);

#pragma unroll
  for (int mi = 0; mi < 2; ++mi) {
#pragma unroll
    for (int u16 = 0; u16 < 2; ++u16) {
      const int j = bn * 32 + u16 * 16 + l15;
      const int ci = mi * 2 + u16;  // float4 index
#pragma unroll
      for (int r = 0; r < 4; ++r) {
        const int brow = bm * BM + w * 32 + mi * 16 + quad * 4 + r;
        float gi = acc[mi][u16 + 0][r] + bias[u16 + 0];
        float gf = acc[mi][u16 + 2][r] + bias[u16 + 2];
        float gg = acc[mi][u16 + 4][r] + bias[u16 + 4];
        float go = acc[mi][u16 + 6][r] + bias[u16 + 6];
        float cn = sigm(gf) * cv[ci][r] + sigm(gi) * tanh_f(gg);
        cv[ci][r] = cn;
        float h = sigm(go) * tanh_f(cn);
        Xn[(size_t)brow * KDIM + EMB + j] = (f16)h;
      }
    }
  }
#pragma unroll
  for (int q = 0; q < 4; ++q) *(float4v*)(cbase + q * 4) = cv[q];

  // ---- fused obs-emb for step t+1 (bn==0 blocks handle their bm strip) ----
  if (do_emb && bn == 0) {
    const int row = bm * BM + (tid >> 1);
    const int jb = (tid & 1) * 32;
    const float* o0 = obs_next + row * 2;
    const float* o1 = o0 + BATCH * 2;
    float d0 = o1[0] - o0[0];
    float d1 = o1[1] - o0[1];
    f16* dst = Xn + (size_t)row * KDIM + jb;
#pragma unroll
    for (int jj = 0; jj < 32; ++jj) {
      int j = jb + jj;
      float v = d0 * W_emb[2 * j] + d1 * W_emb[2 * j + 1] + b_emb[j];
      dst[jj] = (f16)fmaxf(v, 0.f);
    }
  }
}

// ---------------------------------------------------------------------------
// Out-projection (+ optional pred-emb for step t+1): 512 blocks x 256 thr,
// 8 rows/block (2 per wave).
// ---------------------------------------------------------------------------
__global__ __launch_bounds__(256)
void outemb_kernel(const f16* __restrict__ Xh, const float* __restrict__ W_out,
                   const float* __restrict__ b_out, float* __restrict__ out_t,
                   int emb_flag, const float* __restrict__ W_emb,
                   const float* __restrict__ b_emb, f16* __restrict__ Xn) {
  __shared__ float s_nv[8][2];
  const int tid = threadIdx.x;
  const int lane = tid & 63;
  const int w = tid >> 6;
  const int row0 = blockIdx.x * 8;

#pragma unroll
  for (int rr = 0; rr < 2; ++rr) {
    const int row = row0 + w * 2 + rr;
    const f16* hrow = Xh + (size_t)row * KDIM + EMB;
    half8 h0 = *(const half8*)(hrow + lane * 16);
    half8 h1 = *(const half8*)(hrow + lane * 16 + 8);
    float a[5];
#pragma unroll
    for (int o = 0; o < 5; ++o) {
      const float* wo = W_out + o * HID + lane * 16;
      float s = 0.f;
#pragma unroll
      for (int e = 0; e < 8; ++e) s += (float)h0[e] * wo[e];
#pragma unroll
      for (int e = 0; e < 8; ++e) s += (float)h1[e] * wo[8 + e];
      a[o] = s;
    }
#pragma unroll
    for (int sh = 32; sh > 0; sh >>= 1)
#pragma unroll
      for (int o = 0; o < 5; ++o) a[o] += __shfl_down(a[o], sh, 64);
    if (lane == 0) {
#pragma unroll
      for (int o = 0; o < 5; ++o) out_t[(size_t)row * 5 + o] = a[o] + b_out[o];
      s_nv[w * 2 + rr][0] = a[0] + b_out[0];
      s_nv[w * 2 + rr][1] = a[1] + b_out[1];
    }
  }

  if (emb_flag) {
    __syncthreads();
    for (int s = tid; s < 512; s += 256) {
      int rr = s >> 6, jc = s & 63;
      int row = row0 + rr;
      float d0 = s_nv[rr][0], d1 = s_nv[rr][1];
      float v = d0 * W_emb[2 * jc] + d1 * W_emb[2 * jc + 1] + b_emb[jc];
      Xn[(size_t)row * KDIM + jc] = (f16)fmaxf(v, 0.f);
    }
  }
}

// ---------------------------------------------------------------------------
extern "C" void kernel_launch(void* const* d_in, const int* in_sizes, int n_in,
                              void* d_out, int out_size, void* d_ws, size_t ws_size,
                              hipStream_t stream) {
  const float* observed = (const float*)d_in[0];
  const float* W_emb = (const float*)d_in[1];
  const float* b_emb = (const float*)d_in[2];
  const float* W_ih = (const float*)d_in[3];
  const float* b_ih = (const float*)d_in[4];
  const float* W_hh = (const float*)d_in[5];
  const float* b_hh = (const float*)d_in[6];
  const float* W_out = (const float*)d_in[7];
  const float* b_out = (const float*)d_in[8];
  float* out = (float*)d_out;

  uint8_t* ws = (uint8_t*)d_ws;
  const size_t WC_BYTES = (size_t)4096 * KDIM * sizeof(f16);  // 8,912,896
  f16* Wc = (f16*)ws;
  float* bc = (float*)(ws + WC_BYTES);
  f16* X0 = (f16*)(ws + WC_BYTES + 16384);
  f16* X1 = (f16*)(ws + 2 * WC_BYTES + 16384);
  float* c_ws = (float*)(ws + 3 * WC_BYTES + 16384);

  pack_kernel<<<(4096 * KDIM) / 256, 256, 0, stream>>>(W_ih, b_ih, W_hh, b_hh, Wc, bc);
  hipMemsetAsync(X0, 0, WC_BYTES, stream);                       // h0 = 0
  hipMemsetAsync(c_ws, 0, (size_t)BATCH * HID * 4, stream);      // c0 = 0
  emb0_kernel<<<(BATCH * EMB) / 256, 256, 0, stream>>>(observed, W_emb, b_emb, X0);

  for (int t = 0; t < NSTEP; ++t) {
    f16* Xc = (t & 1) ? X1 : X0;
    f16* Xn = (t & 1) ? X0 : X1;
    const int do_emb = (t + 1 < NOBS) ? 1 : 0;
    dim3 grid(BATCH / BN, BATCH / BM);
    gemm_cell_kernel<<<grid, 256, 0, stream>>>(
        Xc, Wc, bc, c_ws, Xn, observed + (size_t)(t + 1) * BATCH * 2, do_emb, W_emb, b_emb);
    const int emb_pred = (t >= 7 && t + 1 < NSTEP) ? 1 : 0;
    outemb_kernel<<<BATCH / 8, 256, 0, stream>>>(
        Xn, W_out, b_out, out + (size_t)t * BATCH * 5, emb_pred, W_emb, b_emb, Xn);
  }
}

// Round 6
// 1233.794 us; speedup vs baseline: 2.4462x; 1.0509x over previous
//
#include <hip/hip_runtime.h>
#include <stdint.h>
#include <stddef.h>

#define BATCH 4096
#define HID   1024
#define EMB   64
#define KDIM  1088
#define NSTEP 19
#define NOBS  8

#define BM 128      // block rows
#define BN 256      // block packed-gate cols
#define BK 32
#define BUFH 12288  // halfs per LDS buffer: A 128x32 (4096) + B 256x32 (8192)

typedef _Float16 f16;
typedef _Float16 half8 __attribute__((ext_vector_type(8)));
typedef float    float4v __attribute__((ext_vector_type(4)));
typedef int      int4v   __attribute__((ext_vector_type(4)));

__device__ __forceinline__ float sigm(float x) { return 1.f / (1.f + __expf(-x)); }
__device__ __forceinline__ float tanh_f(float x) { return 1.f - 2.f / (__expf(2.f * x) + 1.f); }

// K-loop barrier: LDS-only drain + barrier. No vmcnt(0) — register prefetch
// loads stay in flight across it (the whole point vs __syncthreads()).
#define KBAR() asm volatile("s_waitcnt lgkmcnt(0)\n\ts_barrier" ::: "memory")

// ---------------------------------------------------------------------------
// Pack W_ih|W_hh (fp32) -> interleaved fp16 Wc [4096][1088] + combined bias.
// Packed row p = 128*t + 32*g + u  <->  original gate row g*1024 + 32*t + u.
// ---------------------------------------------------------------------------
__global__ void pack_kernel(const float* __restrict__ W_ih, const float* __restrict__ b_ih,
                            const float* __restrict__ W_hh, const float* __restrict__ b_hh,
                            f16* __restrict__ Wc, float* __restrict__ bc) {
  int gid = blockIdx.x * blockDim.x + threadIdx.x;
  int p = gid / KDIM;
  int k = gid - p * KDIM;
  int t = p >> 7;
  int g = (p >> 5) & 3;
  int u = p & 31;
  int orig = g * HID + t * 32 + u;
  float v = (k < EMB) ? W_ih[orig * EMB + k] : W_hh[orig * HID + (k - EMB)];
  Wc[gid] = (f16)v;
  if (k == 0) bc[p] = b_ih[orig] + b_hh[orig];
}

// ---------------------------------------------------------------------------
__global__ void emb0_kernel(const float* __restrict__ observed,
                            const float* __restrict__ W_emb, const float* __restrict__ b_emb,
                            f16* __restrict__ Xc) {
  int gid = blockIdx.x * blockDim.x + threadIdx.x;  // BATCH*EMB
  int b = gid >> 6, j = gid & 63;
  const float* o0 = observed + b * 2;
  const float* o1 = o0 + BATCH * 2;
  float d0 = o1[0] - o0[0];
  float d1 = o1[1] - o0[1];
  float v = d0 * W_emb[2 * j] + d1 * W_emb[2 * j + 1] + b_emb[j];
  Xc[(size_t)b * KDIM + j] = (f16)fmaxf(v, 0.f);
}

// ---------------------------------------------------------------------------
// Fused gates-GEMM + LSTM cell. Block tile 128x256, 4 waves of 64x128.
// Register-staged double-buffered K-loop, one lgkm-only barrier per kt.
// ---------------------------------------------------------------------------
__global__ __launch_bounds__(256, 2)
void gemm_cell_kernel(const f16* __restrict__ Xc, const f16* __restrict__ Wc,
                      const float* __restrict__ bc,
                      float* __restrict__ c_ws, f16* __restrict__ Xn,
                      const float* __restrict__ obs_next, int do_emb,
                      const float* __restrict__ W_emb, const float* __restrict__ b_emb) {
  __shared__ f16 smem[2 * BUFH];
  const int tid = threadIdx.x;
  const int lane = tid & 63;
  const int w = tid >> 6;
  const int l15 = lane & 15;
  const int quad = lane >> 4;
  const int bm = blockIdx.y;   // 0..31
  const int bnB = blockIdx.x;  // 0..15
  const int wM = w & 1;        // 2 x 64 rows
  const int wN = w >> 1;       // 2 x 128 packed cols
  const int tt = bnB * 2 + wN; // this wave's 128-packed-col tile (32 h-cols)

  // ---- staging slot geometry (XOR-swizzled 16B chunks) ----
  // A slots s in {tid, tid+256} of 512; B slots s in {tid,+256,+512,+768} of 1024.
  int sA0 = tid, sA1 = tid + 256;
  int rA0 = sA0 >> 2, cA0 = (sA0 & 3) ^ ((rA0 >> 1) & 3);
  int rA1 = sA1 >> 2, cA1 = (sA1 & 3) ^ ((rA1 >> 1) & 3);
  const f16* gA0 = Xc + (size_t)(bm * BM + rA0) * KDIM + cA0 * 8;
  const f16* gA1 = Xc + (size_t)(bm * BM + rA1) * KDIM + cA1 * 8;
  const int lA0 = sA0 * 8, lA1 = sA1 * 8;

  const f16* gB[4];
  int lB[4];
#pragma unroll
  for (int h = 0; h < 4; ++h) {
    int s = tid + h * 256;
    int r = s >> 2, cl = (s & 3) ^ ((r >> 1) & 3);
    gB[h] = Wc + (size_t)(bnB * BN + r) * KDIM + cl * 8;
    lB[h] = 4096 + s * 8;
  }

  // ---- fragment read offsets (halfs within a buffer) ----
  int a_off[4], b_off[8];
#pragma unroll
  for (int mi = 0; mi < 4; ++mi) {
    int r = wM * 64 + mi * 16 + l15;
    a_off[mi] = r * 32 + ((quad ^ ((r >> 1) & 3)) * 8);
  }
#pragma unroll
  for (int ni = 0; ni < 8; ++ni) {
    int r = wN * 128 + ni * 16 + l15;
    b_off[ni] = 4096 + r * 32 + ((quad ^ ((r >> 1) & 3)) * 8);
  }

  float4v acc[4][8];
#pragma unroll
  for (int mi = 0; mi < 4; ++mi)
#pragma unroll
    for (int ni = 0; ni < 8; ++ni) acc[mi][ni] = (float4v){0.f, 0.f, 0.f, 0.f};

  // ---- pipeline prologue: kt=0 into buf0, prefetch kt=1 ----
  int4v va0 = *(const int4v*)gA0;
  int4v va1 = *(const int4v*)gA1;
  int4v vb0 = *(const int4v*)gB[0];
  int4v vb1 = *(const int4v*)gB[1];
  int4v vb2 = *(const int4v*)gB[2];
  int4v vb3 = *(const int4v*)gB[3];
  *(int4v*)(smem + lA0) = va0;
  *(int4v*)(smem + lA1) = va1;
  *(int4v*)(smem + lB[0]) = vb0;
  *(int4v*)(smem + lB[1]) = vb1;
  *(int4v*)(smem + lB[2]) = vb2;
  *(int4v*)(smem + lB[3]) = vb3;
  va0 = *(const int4v*)(gA0 + BK);
  va1 = *(const int4v*)(gA1 + BK);
  vb0 = *(const int4v*)(gB[0] + BK);
  vb1 = *(const int4v*)(gB[1] + BK);
  vb2 = *(const int4v*)(gB[2] + BK);
  vb3 = *(const int4v*)(gB[3] + BK);
  KBAR();

  for (int kt = 0; kt < KDIM / BK; ++kt) {
    const f16* sb = smem + (kt & 1) * BUFH;
    f16* so = smem + ((kt + 1) & 1) * BUFH;

    if (kt + 1 < KDIM / BK) {
      // commit prefetched kt+1 (vmcnt waits are per-register, inserted here)
      *(int4v*)(so + lA0) = va0;
      *(int4v*)(so + lA1) = va1;
      *(int4v*)(so + lB[0]) = vb0;
      *(int4v*)(so + lB[1]) = vb1;
      *(int4v*)(so + lB[2]) = vb2;
      *(int4v*)(so + lB[3]) = vb3;
      if (kt + 2 < KDIM / BK) {
        const int off = (kt + 2) * BK;
        va0 = *(const int4v*)(gA0 + off);
        va1 = *(const int4v*)(gA1 + off);
        vb0 = *(const int4v*)(gB[0] + off);
        vb1 = *(const int4v*)(gB[1] + off);
        vb2 = *(const int4v*)(gB[2] + off);
        vb3 = *(const int4v*)(gB[3] + off);
      }
    }

    half8 af[4];
#pragma unroll
    for (int mi = 0; mi < 4; ++mi) af[mi] = *(const half8*)(sb + a_off[mi]);
#pragma unroll
    for (int g4 = 0; g4 < 2; ++g4) {
      half8 bf[4];
#pragma unroll
      for (int i = 0; i < 4; ++i) bf[i] = *(const half8*)(sb + b_off[g4 * 4 + i]);
#pragma unroll
      for (int mi = 0; mi < 4; ++mi)
#pragma unroll
        for (int i = 0; i < 4; ++i)
          acc[mi][g4 * 4 + i] =
              __builtin_amdgcn_mfma_f32_16x16x32_f16(af[mi], bf[i], acc[mi][g4 * 4 + i], 0, 0, 0);
    }

    if (kt + 1 < KDIM / BK) KBAR();
  }

  // ---- in-register LSTM cell epilogue (coalesced c-state) ----
  float bias[8];
#pragma unroll
  for (int ni = 0; ni < 8; ++ni) bias[ni] = bc[tt * 128 + ni * 16 + l15];

  float* cbase = c_ws + ((size_t)(blockIdx.y * 16 + blockIdx.x) * 256 + tid) * 32;
  float4v cv[8];
#pragma unroll
  for (int q = 0; q < 8; ++q) cv[q] = *(const float4v*)(cbase + q * 4);

#pragma unroll
  for (int mi = 0; mi < 4; ++mi) {
#pragma unroll
    for (int u16 = 0; u16 < 2; ++u16) {
      const int j = tt * 32 + u16 * 16 + l15;
      const int ci = mi * 2 + u16;
#pragma unroll
      for (int r = 0; r < 4; ++r) {
        const int brow = bm * BM + wM * 64 + mi * 16 + quad * 4 + r;
        float gi = acc[mi][u16 + 0][r] + bias[u16 + 0];
        float gf = acc[mi][u16 + 2][r] + bias[u16 + 2];
        float gg = acc[mi][u16 + 4][r] + bias[u16 + 4];
        float go = acc[mi][u16 + 6][r] + bias[u16 + 6];
        float cn = sigm(gf) * cv[ci][r] + sigm(gi) * tanh_f(gg);
        cv[ci][r] = cn;
        float h = sigm(go) * tanh_f(cn);
        Xn[(size_t)brow * KDIM + EMB + j] = (f16)h;
      }
    }
  }
#pragma unroll
  for (int q = 0; q < 8; ++q) *(float4v*)(cbase + q * 4) = cv[q];

  // ---- fused obs-emb for step t+1 (bnB==0 blocks handle their bm strip) ----
  if (do_emb && bnB == 0) {
    const int row = bm * BM + (tid >> 1);
    const int jb = (tid & 1) * 32;
    const float* o0 = obs_next + row * 2;
    const float* o1 = o0 + BATCH * 2;
    float d0 = o1[0] - o0[0];
    float d1 = o1[1] - o0[1];
    f16* dst = Xn + (size_t)row * KDIM + jb;
#pragma unroll
    for (int jj = 0; jj < 32; ++jj) {
      int j = jb + jj;
      float v = d0 * W_emb[2 * j] + d1 * W_emb[2 * j + 1] + b_emb[j];
      dst[jj] = (f16)fmaxf(v, 0.f);
    }
  }
}

// ---------------------------------------------------------------------------
// Out-projection (+ optional pred-emb for step t+1): 8 rows/block.
// ---------------------------------------------------------------------------
__global__ __launch_bounds__(256)
void outemb_kernel(const f16* __restrict__ Xh, const float* __restrict__ W_out,
                   const float* __restrict__ b_out, float* __restrict__ out_t,
                   int emb_flag, const float* __restrict__ W_emb,
                   const float* __restrict__ b_emb, f16* __restrict__ Xn) {
  __shared__ float s_nv[8][2];
  const int tid = threadIdx.x;
  const int lane = tid & 63;
  const int w = tid >> 6;
  const int row0 = blockIdx.x * 8;

#pragma unroll
  for (int rr = 0; rr < 2; ++rr) {
    const int row = row0 + w * 2 + rr;
    const f16* hrow = Xh + (size_t)row * KDIM + EMB;
    half8 h0 = *(const half8*)(hrow + lane * 16);
    half8 h1 = *(const half8*)(hrow + lane * 16 + 8);
    float a[5];
#pragma unroll
    for (int o = 0; o < 5; ++o) {
      const float* wo = W_out + o * HID + lane * 16;
      float s = 0.f;
#pragma unroll
      for (int e = 0; e < 8; ++e) s += (float)h0[e] * wo[e];
#pragma unroll
      for (int e = 0; e < 8; ++e) s += (float)h1[e] * wo[8 + e];
      a[o] = s;
    }
#pragma unroll
    for (int sh = 32; sh > 0; sh >>= 1)
#pragma unroll
      for (int o = 0; o < 5; ++o) a[o] += __shfl_down(a[o], sh, 64);
    if (lane == 0) {
#pragma unroll
      for (int o = 0; o < 5; ++o) out_t[(size_t)row * 5 + o] = a[o] + b_out[o];
      s_nv[w * 2 + rr][0] = a[0] + b_out[0];
      s_nv[w * 2 + rr][1] = a[1] + b_out[1];
    }
  }

  if (emb_flag) {
    __syncthreads();
    for (int s = tid; s < 512; s += 256) {
      int rr = s >> 6, jc = s & 63;
      int row = row0 + rr;
      float d0 = s_nv[rr][0], d1 = s_nv[rr][1];
      float v = d0 * W_emb[2 * jc] + d1 * W_emb[2 * jc + 1] + b_emb[jc];
      Xn[(size_t)row * KDIM + jc] = (f16)fmaxf(v, 0.f);
    }
  }
}

// ---------------------------------------------------------------------------
extern "C" void kernel_launch(void* const* d_in, const int* in_sizes, int n_in,
                              void* d_out, int out_size, void* d_ws, size_t ws_size,
                              hipStream_t stream) {
  const float* observed = (const float*)d_in[0];
  const float* W_emb = (const float*)d_in[1];
  const float* b_emb = (const float*)d_in[2];
  const float* W_ih = (const float*)d_in[3];
  const float* b_ih = (const float*)d_in[4];
  const float* W_hh = (const float*)d_in[5];
  const float* b_hh = (const float*)d_in[6];
  const float* W_out = (const float*)d_in[7];
  const float* b_out = (const float*)d_in[8];
  float* out = (float*)d_out;

  uint8_t* ws = (uint8_t*)d_ws;
  const size_t WC_BYTES = (size_t)4096 * KDIM * sizeof(f16);  // 8,912,896
  f16* Wc = (f16*)ws;
  float* bc = (float*)(ws + WC_BYTES);
  f16* X0 = (f16*)(ws + WC_BYTES + 16384);
  f16* X1 = (f16*)(ws + 2 * WC_BYTES + 16384);
  float* c_ws = (float*)(ws + 3 * WC_BYTES + 16384);

  pack_kernel<<<(4096 * KDIM) / 256, 256, 0, stream>>>(W_ih, b_ih, W_hh, b_hh, Wc, bc);
  hipMemsetAsync(X0, 0, WC_BYTES, stream);                       // h0 = 0
  hipMemsetAsync(c_ws, 0, (size_t)BATCH * HID * 4, stream);      // c0 = 0
  emb0_kernel<<<(BATCH * EMB) / 256, 256, 0, stream>>>(observed, W_emb, b_emb, X0);

  for (int t = 0; t < NSTEP; ++t) {
    f16* Xc = (t & 1) ? X1 : X0;
    f16* Xn = (t & 1) ? X0 : X1;
    const int do_emb = (t + 1 < NOBS) ? 1 : 0;
    dim3 grid(BATCH / BN, BATCH / BM);  // (16, 32)
    gemm_cell_kernel<<<grid, 256, 0, stream>>>(
        Xc, Wc, bc, c_ws, Xn, observed + (size_t)(t + 1) * BATCH * 2, do_emb, W_emb, b_emb);
    const int emb_pred = (t >= 7 && t + 1 < NSTEP) ? 1 : 0;
    outemb_kernel<<<BATCH / 8, 256, 0, stream>>>(
        Xn, W_out, b_out, out + (size_t)t * BATCH * 5, emb_pred, W_emb, b_emb, Xn);
  }
}

// Round 7
// 1210.561 us; speedup vs baseline: 2.4931x; 1.0192x over previous
//
#include <hip/hip_runtime.h>
#include <stdint.h>
#include <stddef.h>

#define BATCH 4096
#define HID   1024
#define EMB   64
#define KDIM  1088
#define NSTEP 19
#define NOBS  8

#define BM 128      // block rows
#define BN 256      // block packed-gate cols
#define BK 32
#define BUFH 12288  // halfs per LDS buffer: A 128x32 (4096) + B 256x32 (8192)

typedef _Float16 f16;
typedef _Float16 half8 __attribute__((ext_vector_type(8)));
typedef float    float4v __attribute__((ext_vector_type(4)));
typedef int      int4v   __attribute__((ext_vector_type(4)));

__device__ __forceinline__ float sigm(float x) { return 1.f / (1.f + __expf(-x)); }
__device__ __forceinline__ float tanh_f(float x) { return 1.f - 2.f / (__expf(2.f * x) + 1.f); }

// K-loop barrier: LDS-only drain + barrier. No vmcnt(0) — register prefetch
// loads stay in flight across it.
#define KBAR() asm volatile("s_waitcnt lgkmcnt(0)\n\ts_barrier" ::: "memory")

// ---------------------------------------------------------------------------
// Pack W_ih|W_hh (fp32) -> interleaved fp16 Wc [4096][1088] + combined bias.
// Packed row p = 128*t + 32*g + u  <->  original gate row g*1024 + 32*t + u.
// ---------------------------------------------------------------------------
__global__ void pack_kernel(const float* __restrict__ W_ih, const float* __restrict__ b_ih,
                            const float* __restrict__ W_hh, const float* __restrict__ b_hh,
                            f16* __restrict__ Wc, float* __restrict__ bc) {
  int gid = blockIdx.x * blockDim.x + threadIdx.x;
  int p = gid / KDIM;
  int k = gid - p * KDIM;
  int t = p >> 7;
  int g = (p >> 5) & 3;
  int u = p & 31;
  int orig = g * HID + t * 32 + u;
  float v = (k < EMB) ? W_ih[orig * EMB + k] : W_hh[orig * HID + (k - EMB)];
  Wc[gid] = (f16)v;
  if (k == 0) bc[p] = b_ih[orig] + b_hh[orig];
}

// ---------------------------------------------------------------------------
__global__ void emb0_kernel(const float* __restrict__ observed,
                            const float* __restrict__ W_emb, const float* __restrict__ b_emb,
                            f16* __restrict__ Xc) {
  int gid = blockIdx.x * blockDim.x + threadIdx.x;  // BATCH*EMB
  int b = gid >> 6, j = gid & 63;
  const float* o0 = observed + b * 2;
  const float* o1 = o0 + BATCH * 2;
  float d0 = o1[0] - o0[0];
  float d1 = o1[1] - o0[1];
  float v = d0 * W_emb[2 * j] + d1 * W_emb[2 * j + 1] + b_emb[j];
  Xc[(size_t)b * KDIM + j] = (f16)fmaxf(v, 0.f);
}

// ---------------------------------------------------------------------------
// Fused gates-GEMM + LSTM cell. Block tile 128x256, 4 waves of 64x128.
// Register-staged double-buffered K-loop, one lgkm-only barrier per kt.
// Schedule: reads g0 -> MFMA g0 -> commit writes + next loads -> reads g1 ->
// MFMA g1 -> KBAR  (vmcnt waits covered by MFMA g0).
// ---------------------------------------------------------------------------
__global__ __launch_bounds__(256, 2)
void gemm_cell_kernel(const f16* __restrict__ Xc, const f16* __restrict__ Wc,
                      const float* __restrict__ bc,
                      float* __restrict__ c_ws, f16* __restrict__ Xn,
                      const float* __restrict__ obs_next, int do_emb,
                      const float* __restrict__ W_emb, const float* __restrict__ b_emb) {
  __shared__ f16 smem[2 * BUFH];
  const int tid = threadIdx.x;
  const int lane = tid & 63;
  const int w = tid >> 6;
  const int l15 = lane & 15;
  const int quad = lane >> 4;
  const int bm = blockIdx.y;   // 0..31
  const int bnB = blockIdx.x;  // 0..15
  const int wM = w & 1;        // 2 x 64 rows
  const int wN = w >> 1;       // 2 x 128 packed cols
  const int tt = bnB * 2 + wN; // this wave's 128-packed-col tile (32 h-cols)

  // ---- staging slot geometry (XOR-swizzled 16B chunks) ----
  int sA0 = tid, sA1 = tid + 256;
  int rA0 = sA0 >> 2, cA0 = (sA0 & 3) ^ ((rA0 >> 1) & 3);
  int rA1 = sA1 >> 2, cA1 = (sA1 & 3) ^ ((rA1 >> 1) & 3);
  const f16* gA0 = Xc + (size_t)(bm * BM + rA0) * KDIM + cA0 * 8;
  const f16* gA1 = Xc + (size_t)(bm * BM + rA1) * KDIM + cA1 * 8;
  const int lA0 = sA0 * 8, lA1 = sA1 * 8;

  const f16* gB[4];
  int lB[4];
#pragma unroll
  for (int h = 0; h < 4; ++h) {
    int s = tid + h * 256;
    int r = s >> 2, cl = (s & 3) ^ ((r >> 1) & 3);
    gB[h] = Wc + (size_t)(bnB * BN + r) * KDIM + cl * 8;
    lB[h] = 4096 + s * 8;
  }

  // ---- fragment read offsets (halfs within a buffer) ----
  int a_off[4], b_off[8];
#pragma unroll
  for (int mi = 0; mi < 4; ++mi) {
    int r = wM * 64 + mi * 16 + l15;
    a_off[mi] = r * 32 + ((quad ^ ((r >> 1) & 3)) * 8);
  }
#pragma unroll
  for (int ni = 0; ni < 8; ++ni) {
    int r = wN * 128 + ni * 16 + l15;
    b_off[ni] = 4096 + r * 32 + ((quad ^ ((r >> 1) & 3)) * 8);
  }

  float4v acc[4][8];
#pragma unroll
  for (int mi = 0; mi < 4; ++mi)
#pragma unroll
    for (int ni = 0; ni < 8; ++ni) acc[mi][ni] = (float4v){0.f, 0.f, 0.f, 0.f};

  // ---- pipeline prologue: kt=0 into buf0, prefetch kt=1 into regs ----
  int4v va0 = *(const int4v*)gA0;
  int4v va1 = *(const int4v*)gA1;
  int4v vb0 = *(const int4v*)gB[0];
  int4v vb1 = *(const int4v*)gB[1];
  int4v vb2 = *(const int4v*)gB[2];
  int4v vb3 = *(const int4v*)gB[3];
  *(int4v*)(smem + lA0) = va0;
  *(int4v*)(smem + lA1) = va1;
  *(int4v*)(smem + lB[0]) = vb0;
  *(int4v*)(smem + lB[1]) = vb1;
  *(int4v*)(smem + lB[2]) = vb2;
  *(int4v*)(smem + lB[3]) = vb3;
  va0 = *(const int4v*)(gA0 + BK);
  va1 = *(const int4v*)(gA1 + BK);
  vb0 = *(const int4v*)(gB[0] + BK);
  vb1 = *(const int4v*)(gB[1] + BK);
  vb2 = *(const int4v*)(gB[2] + BK);
  vb3 = *(const int4v*)(gB[3] + BK);
  KBAR();

  for (int kt = 0; kt < KDIM / BK; ++kt) {
    const f16* sb = smem + (kt & 1) * BUFH;
    f16* so = smem + ((kt + 1) & 1) * BUFH;

    // fragment reads, group 0 (A + first 4 B)
    half8 af[4];
#pragma unroll
    for (int mi = 0; mi < 4; ++mi) af[mi] = *(const half8*)(sb + a_off[mi]);
    half8 bf0[4];
#pragma unroll
    for (int i = 0; i < 4; ++i) bf0[i] = *(const half8*)(sb + b_off[i]);

    // MFMA group 0 — covers the vmcnt waits of the write commits below
#pragma unroll
    for (int mi = 0; mi < 4; ++mi)
#pragma unroll
      for (int i = 0; i < 4; ++i)
        acc[mi][i] = __builtin_amdgcn_mfma_f32_16x16x32_f16(af[mi], bf0[i], acc[mi][i], 0, 0, 0);

    if (kt + 1 < KDIM / BK) {
      // commit prefetched kt+1 to the other buffer
      *(int4v*)(so + lA0) = va0;
      *(int4v*)(so + lA1) = va1;
      *(int4v*)(so + lB[0]) = vb0;
      *(int4v*)(so + lB[1]) = vb1;
      *(int4v*)(so + lB[2]) = vb2;
      *(int4v*)(so + lB[3]) = vb3;
      if (kt + 2 < KDIM / BK) {
        const int off = (kt + 2) * BK;
        va0 = *(const int4v*)(gA0 + off);
        va1 = *(const int4v*)(gA1 + off);
        vb0 = *(const int4v*)(gB[0] + off);
        vb1 = *(const int4v*)(gB[1] + off);
        vb2 = *(const int4v*)(gB[2] + off);
        vb3 = *(const int4v*)(gB[3] + off);
      }
    }

    // fragment reads, group 1 (issued after writes -> their lgkm wait
    // lands after writes retire; covered by MFMA group 0 issue window)
    half8 bf1[4];
#pragma unroll
    for (int i = 0; i < 4; ++i) bf1[i] = *(const half8*)(sb + b_off[4 + i]);

    // MFMA group 1
#pragma unroll
    for (int mi = 0; mi < 4; ++mi)
#pragma unroll
      for (int i = 0; i < 4; ++i)
        acc[mi][4 + i] = __builtin_amdgcn_mfma_f32_16x16x32_f16(af[mi], bf1[i], acc[mi][4 + i], 0, 0, 0);

    if (kt + 1 < KDIM / BK) KBAR();
  }

  // ---- in-register LSTM cell epilogue (coalesced c-state) ----
  float bias[8];
#pragma unroll
  for (int ni = 0; ni < 8; ++ni) bias[ni] = bc[tt * 128 + ni * 16 + l15];

  float* cbase = c_ws + ((size_t)(blockIdx.y * 16 + blockIdx.x) * 256 + tid) * 32;
  float4v cv[8];
#pragma unroll
  for (int q = 0; q < 8; ++q) cv[q] = *(const float4v*)(cbase + q * 4);

#pragma unroll
  for (int mi = 0; mi < 4; ++mi) {
#pragma unroll
    for (int u16 = 0; u16 < 2; ++u16) {
      const int j = tt * 32 + u16 * 16 + l15;
      const int ci = mi * 2 + u16;
#pragma unroll
      for (int r = 0; r < 4; ++r) {
        const int brow = bm * BM + wM * 64 + mi * 16 + quad * 4 + r;
        float gi = acc[mi][u16 + 0][r] + bias[u16 + 0];
        float gf = acc[mi][u16 + 2][r] + bias[u16 + 2];
        float gg = acc[mi][u16 + 4][r] + bias[u16 + 4];
        float go = acc[mi][u16 + 6][r] + bias[u16 + 6];
        float cn = sigm(gf) * cv[ci][r] + sigm(gi) * tanh_f(gg);
        cv[ci][r] = cn;
        float h = sigm(go) * tanh_f(cn);
        Xn[(size_t)brow * KDIM + EMB + j] = (f16)h;
      }
    }
  }
#pragma unroll
  for (int q = 0; q < 8; ++q) *(float4v*)(cbase + q * 4) = cv[q];

  // ---- fused obs-emb for step t+1 (bnB==0 blocks handle their bm strip) ----
  if (do_emb && bnB == 0) {
    const int row = bm * BM + (tid >> 1);
    const int jb = (tid & 1) * 32;
    const float* o0 = obs_next + row * 2;
    const float* o1 = o0 + BATCH * 2;
    float d0 = o1[0] - o0[0];
    float d1 = o1[1] - o0[1];
    f16* dst = Xn + (size_t)row * KDIM + jb;
#pragma unroll
    for (int jj = 0; jj < 32; ++jj) {
      int j = jb + jj;
      float v = d0 * W_emb[2 * j] + d1 * W_emb[2 * j + 1] + b_emb[j];
      dst[jj] = (f16)fmaxf(v, 0.f);
    }
  }
}

// ---------------------------------------------------------------------------
// Out-projection (+ optional pred-emb for step t+1): 8 rows/block.
// ---------------------------------------------------------------------------
__global__ __launch_bounds__(256)
void outemb_kernel(const f16* __restrict__ Xh, const float* __restrict__ W_out,
                   const float* __restrict__ b_out, float* __restrict__ out_t,
                   int emb_flag, const float* __restrict__ W_emb,
                   const float* __restrict__ b_emb, f16* __restrict__ Xn) {
  __shared__ float s_nv[8][2];
  const int tid = threadIdx.x;
  const int lane = tid & 63;
  const int w = tid >> 6;
  const int row0 = blockIdx.x * 8;

#pragma unroll
  for (int rr = 0; rr < 2; ++rr) {
    const int row = row0 + w * 2 + rr;
    const f16* hrow = Xh + (size_t)row * KDIM + EMB;
    half8 h0 = *(const half8*)(hrow + lane * 16);
    half8 h1 = *(const half8*)(hrow + lane * 16 + 8);
    float a[5];
#pragma unroll
    for (int o = 0; o < 5; ++o) {
      const float* wo = W_out + o * HID + lane * 16;
      float s = 0.f;
#pragma unroll
      for (int e = 0; e < 8; ++e) s += (float)h0[e] * wo[e];
#pragma unroll
      for (int e = 0; e < 8; ++e) s += (float)h1[e] * wo[8 + e];
      a[o] = s;
    }
#pragma unroll
    for (int sh = 32; sh > 0; sh >>= 1)
#pragma unroll
      for (int o = 0; o < 5; ++o) a[o] += __shfl_down(a[o], sh, 64);
    if (lane == 0) {
#pragma unroll
      for (int o = 0; o < 5; ++o) out_t[(size_t)row * 5 + o] = a[o] + b_out[o];
      s_nv[w * 2 + rr][0] = a[0] + b_out[0];
      s_nv[w * 2 + rr][1] = a[1] + b_out[1];
    }
  }

  if (emb_flag) {
    __syncthreads();
    for (int s = tid; s < 512; s += 256) {
      int rr = s >> 6, jc = s & 63;
      int row = row0 + rr;
      float d0 = s_nv[rr][0], d1 = s_nv[rr][1];
      float v = d0 * W_emb[2 * jc] + d1 * W_emb[2 * jc + 1] + b_emb[jc];
      Xn[(size_t)row * KDIM + jc] = (f16)fmaxf(v, 0.f);
    }
  }
}

// ---------------------------------------------------------------------------
extern "C" void kernel_launch(void* const* d_in, const int* in_sizes, int n_in,
                              void* d_out, int out_size, void* d_ws, size_t ws_size,
                              hipStream_t stream) {
  const float* observed = (const float*)d_in[0];
  const float* W_emb = (const float*)d_in[1];
  const float* b_emb = (const float*)d_in[2];
  const float* W_ih = (const float*)d_in[3];
  const float* b_ih = (const float*)d_in[4];
  const float* W_hh = (const float*)d_in[5];
  const float* b_hh = (const float*)d_in[6];
  const float* W_out = (const float*)d_in[7];
  const float* b_out = (const float*)d_in[8];
  float* out = (float*)d_out;

  uint8_t* ws = (uint8_t*)d_ws;
  const size_t WC_BYTES = (size_t)4096 * KDIM * sizeof(f16);  // 8,912,896
  f16* Wc = (f16*)ws;
  float* bc = (float*)(ws + WC_BYTES);
  f16* X0 = (f16*)(ws + WC_BYTES + 16384);
  f16* X1 = (f16*)(ws + 2 * WC_BYTES + 16384);
  float* c_ws = (float*)(ws + 3 * WC_BYTES + 16384);

  pack_kernel<<<(4096 * KDIM) / 256, 256, 0, stream>>>(W_ih, b_ih, W_hh, b_hh, Wc, bc);
  hipMemsetAsync(X0, 0, WC_BYTES, stream);                       // h0 = 0
  hipMemsetAsync(c_ws, 0, (size_t)BATCH * HID * 4, stream);      // c0 = 0
  emb0_kernel<<<(BATCH * EMB) / 256, 256, 0, stream>>>(observed, W_emb, b_emb, X0);

  for (int t = 0; t < NSTEP; ++t) {
    f16* Xc = (t & 1) ? X1 : X0;
    f16* Xn = (t & 1) ? X0 : X1;
    const int do_emb = (t + 1 < NOBS) ? 1 : 0;
    dim3 grid(BATCH / BN, BATCH / BM);  // (16, 32)
    gemm_cell_kernel<<<grid, 256, 0, stream>>>(
        Xc, Wc, bc, c_ws, Xn, observed + (size_t)(t + 1) * BATCH * 2, do_emb, W_emb, b_emb);
    const int emb_pred = (t >= 7 && t + 1 < NSTEP) ? 1 : 0;
    outemb_kernel<<<BATCH / 8, 256, 0, stream>>>(
        Xn, W_out, b_out, out + (size_t)t * BATCH * 5, emb_pred, W_emb, b_emb, Xn);
  }
}

// Round 8
// 1099.972 us; speedup vs baseline: 2.7437x; 1.1005x over previous
//
#include <hip/hip_runtime.h>
#include <stdint.h>
#include <stddef.h>

#define BATCH 4096
#define HID   1024
#define EMB   64
#define KDIM  1088
#define NKT   34     // KDIM / 32
#define NSTEP 19
#define NOBS  8

typedef _Float16 f16;
typedef _Float16 half8 __attribute__((ext_vector_type(8)));
typedef float    float4v __attribute__((ext_vector_type(4)));

__device__ __forceinline__ float sigm(float x) { return 1.f / (1.f + __expf(-x)); }
__device__ __forceinline__ float tanh_f(float x) { return 1.f - 2.f / (__expf(2.f * x) + 1.f); }

// ---------------------------------------------------------------------------
// Fragment-major X layout: chunk ((row>>4)*34 + (k>>5))*64 + lane, elem k&7,
// where lane = (row&15) + 16*((k>>3)&3)  — exactly the 16x16x32 A-operand.
// ---------------------------------------------------------------------------
__device__ __forceinline__ int xf_idx(int row, int k) {
  return ((((row >> 4) * NKT + (k >> 5)) * 64) + (row & 15) + (((k >> 3) & 3) << 4)) * 8 + (k & 7);
}

// ---------------------------------------------------------------------------
// Pack W_ih|W_hh -> fragment-major fp16 Wsw. Packed gate-col p = 128t+32g+u
// (gate interleave: a 128-pcol tile = i,f,g,o for 32 h-cols). Fragment-major:
// element gid: j=gid&7, lane=(gid>>3)&63, c16=(gid>>9)&255, kt=gid>>17;
// p = c16*16 + (lane&15), k = kt*32 + (lane>>4)*8 + j.
// ---------------------------------------------------------------------------
__global__ void pack_kernel(const float* __restrict__ W_ih, const float* __restrict__ b_ih,
                            const float* __restrict__ W_hh, const float* __restrict__ b_hh,
                            f16* __restrict__ Wsw, float* __restrict__ bc) {
  int gid = blockIdx.x * blockDim.x + threadIdx.x;  // 4096*1088
  int j = gid & 7;
  int lane = (gid >> 3) & 63;
  int c16 = (gid >> 9) & 255;
  int kt = gid >> 17;
  int p = c16 * 16 + (lane & 15);
  int k = kt * 32 + ((lane >> 4) << 3) + j;
  int t = p >> 7, g = (p >> 5) & 3, u = p & 31;
  int orig = g * HID + t * 32 + u;
  float val = (k < EMB) ? W_ih[orig * EMB + k] : W_hh[orig * HID + (k - EMB)];
  Wsw[gid] = (f16)val;
  if (k == 0) bc[p] = b_ih[orig] + b_hh[orig];
}

// ---------------------------------------------------------------------------
__global__ void emb0_kernel(const float* __restrict__ observed,
                            const float* __restrict__ W_emb, const float* __restrict__ b_emb,
                            f16* __restrict__ Xf) {
  int gid = blockIdx.x * blockDim.x + threadIdx.x;  // BATCH*EMB
  int b = gid >> 6, j = gid & 63;
  const float* o0 = observed + b * 2;
  const float* o1 = o0 + BATCH * 2;
  float d0 = o1[0] - o0[0];
  float d1 = o1[1] - o0[1];
  float v = d0 * W_emb[2 * j] + d1 * W_emb[2 * j + 1] + b_emb[j];
  Xf[xf_idx(b, j)] = (f16)fmaxf(v, 0.f);
}

// ---------------------------------------------------------------------------
// Fused gates-GEMM + LSTM cell. No LDS, no barriers: both operands stream
// fragment-major from global (L2/L3-hot) straight into MFMA, register
// double-buffered. Block: 4 waves stacked in M (256 rows) x 128 pcols.
// ---------------------------------------------------------------------------
__global__ __launch_bounds__(256, 2)
void gemm_cell_kernel(const f16* __restrict__ Xf, const f16* __restrict__ Wsw,
                      const float* __restrict__ bc,
                      float* __restrict__ c_ws, f16* __restrict__ Xn,
                      const float* __restrict__ obs_next, int do_emb,
                      const float* __restrict__ W_emb, const float* __restrict__ b_emb) {
  const int tid = threadIdx.x;
  const int lane = tid & 63;
  const int w = tid >> 6;
  const int l15 = lane & 15;
  const int quad = lane >> 4;
  const int tt = blockIdx.x;            // N tile: 128 pcols = 32 h-cols
  const int mB = blockIdx.y;            // M block: 256 rows
  const int rt0 = mB * 16 + w * 4;      // this wave's first rowtile

  const f16* aB = Xf + (size_t)rt0 * (NKT * 512) + lane * 8;   // +mi*NKT*512 +kt*512
  const f16* bB = Wsw + (size_t)tt * 8 * 512 + lane * 8;       // +ni*512 +kt*131072

  float4v acc[4][8];
#pragma unroll
  for (int mi = 0; mi < 4; ++mi)
#pragma unroll
    for (int ni = 0; ni < 8; ++ni) acc[mi][ni] = (float4v){0.f, 0.f, 0.f, 0.f};

  half8 afA[4], bfA[8], afB[4], bfB[8];

#define LOADF(af, bf, kt)                                                          \
  do {                                                                             \
    _Pragma("unroll") for (int mi = 0; mi < 4; ++mi)                               \
        af[mi] = *(const half8*)(aB + mi * (NKT * 512) + (kt) * 512);              \
    _Pragma("unroll") for (int ni = 0; ni < 8; ++ni)                               \
        bf[ni] = *(const half8*)(bB + ni * 512 + (kt) * 131072);                   \
  } while (0)

#define MFMA_ALL(af, bf)                                                           \
  do {                                                                             \
    _Pragma("unroll") for (int mi = 0; mi < 4; ++mi)                               \
    _Pragma("unroll") for (int ni = 0; ni < 8; ++ni)                               \
        acc[mi][ni] =                                                              \
            __builtin_amdgcn_mfma_f32_16x16x32_f16(af[mi], bf[ni], acc[mi][ni], 0, 0, 0); \
  } while (0)

  LOADF(afA, bfA, 0);
  for (int i = 0; i < NKT / 2; ++i) {
    const int k1 = 2 * i + 1;
    LOADF(afB, bfB, k1);
    MFMA_ALL(afA, bfA);
    if (k1 + 1 < NKT) LOADF(afA, bfA, k1 + 1);
    MFMA_ALL(afB, bfB);
  }
#undef LOADF
#undef MFMA_ALL

  // ---- in-register LSTM cell epilogue (coalesced fp32 c-state) ----
  float bias[8];
#pragma unroll
  for (int ni = 0; ni < 8; ++ni) bias[ni] = bc[tt * 128 + ni * 16 + l15];

  float* cbase = c_ws + ((size_t)(mB * 32 + tt) * 256 + tid) * 32;
  float4v cv[8];
#pragma unroll
  for (int q = 0; q < 8; ++q) cv[q] = *(const float4v*)(cbase + q * 4);

#pragma unroll
  for (int mi = 0; mi < 4; ++mi) {
#pragma unroll
    for (int u16 = 0; u16 < 2; ++u16) {
      const int j = tt * 32 + u16 * 16 + l15;   // h-col
      const int ci = mi * 2 + u16;
#pragma unroll
      for (int r = 0; r < 4; ++r) {
        const int row = mB * 256 + w * 64 + mi * 16 + quad * 4 + r;
        float gi = acc[mi][u16 + 0][r] + bias[u16 + 0];
        float gf = acc[mi][u16 + 2][r] + bias[u16 + 2];
        float gg = acc[mi][u16 + 4][r] + bias[u16 + 4];
        float go = acc[mi][u16 + 6][r] + bias[u16 + 6];
        float cn = sigm(gf) * cv[ci][r] + sigm(gi) * tanh_f(gg);
        cv[ci][r] = cn;
        float h = sigm(go) * tanh_f(cn);
        Xn[xf_idx(row, EMB + j)] = (f16)h;
      }
    }
  }
#pragma unroll
  for (int q = 0; q < 8; ++q) *(float4v*)(cbase + q * 4) = cv[q];

  // ---- fused obs-emb for step t+1 (tt==0 blocks cover their 256 rows) ----
  if (do_emb && tt == 0) {
    const int row = mB * 256 + tid;
    const float* o0 = obs_next + row * 2;
    const float* o1 = o0 + BATCH * 2;
    float d0 = o1[0] - o0[0];
    float d1 = o1[1] - o0[1];
#pragma unroll
    for (int j = 0; j < EMB; ++j) {
      float v = d0 * W_emb[2 * j] + d1 * W_emb[2 * j + 1] + b_emb[j];
      Xn[xf_idx(row, j)] = (f16)fmaxf(v, 0.f);
    }
  }
}

// ---------------------------------------------------------------------------
// Out-projection from fragment-major h (+ optional pred-emb for t+1).
// One block per rowtile (16 rows); wave w covers kt = 2+w, +4...
// ---------------------------------------------------------------------------
__global__ __launch_bounds__(256)
void outemb_kernel(const f16* __restrict__ Xh, const float* __restrict__ W_out,
                   const float* __restrict__ b_out, float* __restrict__ out_t,
                   int emb_flag, const float* __restrict__ W_emb,
                   const float* __restrict__ b_emb, f16* __restrict__ Xn) {
  __shared__ float red[4][16][5];
  __shared__ float s_nv[16][2];
  const int tid = threadIdx.x;
  const int lane = tid & 63;
  const int w = tid >> 6;
  const int l15 = lane & 15;
  const int quad = lane >> 4;
  const int rt = blockIdx.x;  // rowtile

  float a[5] = {0.f, 0.f, 0.f, 0.f, 0.f};
#pragma unroll
  for (int i = 0; i < 8; ++i) {
    const int kt = 2 + w + 4 * i;  // h region: kt in [2,34)
    half8 hv = *(const half8*)(Xh + ((rt * NKT + kt) * 64 + lane) * 8);
    const float* wo = W_out + kt * 32 + quad * 8 - EMB;  // k-EMB offset into W_out row
#pragma unroll
    for (int o = 0; o < 5; ++o) {
      const float* wp = wo + o * HID;
      float s = 0.f;
#pragma unroll
      for (int e = 0; e < 8; ++e) s += (float)hv[e] * wp[e];
      a[o] += s;
    }
  }
#pragma unroll
  for (int o = 0; o < 5; ++o) {
    a[o] += __shfl_xor(a[o], 16, 64);
    a[o] += __shfl_xor(a[o], 32, 64);
  }
  if (quad == 0)
#pragma unroll
    for (int o = 0; o < 5; ++o) red[w][l15][o] = a[o];
  __syncthreads();
  if (tid < 80) {
    const int row = tid / 5, o = tid - row * 5;
    float v = red[0][row][o] + red[1][row][o] + red[2][row][o] + red[3][row][o] + b_out[o];
    out_t[(size_t)(rt * 16 + row) * 5 + o] = v;
    if (o < 2) s_nv[row][o] = v;
  }
  if (emb_flag) {
    __syncthreads();
    for (int s = tid; s < 1024; s += 256) {
      const int rr = s >> 6, jc = s & 63;
      const int row = rt * 16 + rr;
      float d0 = s_nv[rr][0], d1 = s_nv[rr][1];
      float v = d0 * W_emb[2 * jc] + d1 * W_emb[2 * jc + 1] + b_emb[jc];
      Xn[xf_idx(row, jc)] = (f16)fmaxf(v, 0.f);
    }
  }
}

// ---------------------------------------------------------------------------
extern "C" void kernel_launch(void* const* d_in, const int* in_sizes, int n_in,
                              void* d_out, int out_size, void* d_ws, size_t ws_size,
                              hipStream_t stream) {
  const float* observed = (const float*)d_in[0];
  const float* W_emb = (const float*)d_in[1];
  const float* b_emb = (const float*)d_in[2];
  const float* W_ih = (const float*)d_in[3];
  const float* b_ih = (const float*)d_in[4];
  const float* W_hh = (const float*)d_in[5];
  const float* b_hh = (const float*)d_in[6];
  const float* W_out = (const float*)d_in[7];
  const float* b_out = (const float*)d_in[8];
  float* out = (float*)d_out;

  uint8_t* ws = (uint8_t*)d_ws;
  const size_t WC_BYTES = (size_t)4096 * KDIM * sizeof(f16);  // 8,912,896
  f16* Wsw = (f16*)ws;
  float* bc = (float*)(ws + WC_BYTES);
  f16* X0 = (f16*)(ws + WC_BYTES + 16384);
  f16* X1 = (f16*)(ws + 2 * WC_BYTES + 16384);
  float* c_ws = (float*)(ws + 3 * WC_BYTES + 16384);

  pack_kernel<<<(4096 * KDIM) / 256, 256, 0, stream>>>(W_ih, b_ih, W_hh, b_hh, Wsw, bc);
  hipMemsetAsync(X0, 0, WC_BYTES, stream);                   // h0 = 0 (emb written below)
  hipMemsetAsync(c_ws, 0, (size_t)BATCH * HID * 4, stream);  // c0 = 0
  emb0_kernel<<<(BATCH * EMB) / 256, 256, 0, stream>>>(observed, W_emb, b_emb, X0);

  for (int t = 0; t < NSTEP; ++t) {
    f16* Xc = (t & 1) ? X1 : X0;
    f16* Xn = (t & 1) ? X0 : X1;
    const int do_emb = (t + 1 < NOBS) ? 1 : 0;
    dim3 grid(32, 16);  // x: N tiles (128 pcols), y: M blocks (256 rows)
    gemm_cell_kernel<<<grid, 256, 0, stream>>>(
        Xc, Wsw, bc, c_ws, Xn, observed + (size_t)(t + 1) * BATCH * 2, do_emb, W_emb, b_emb);
    const int emb_pred = (t >= 7 && t + 1 < NSTEP) ? 1 : 0;
    outemb_kernel<<<BATCH / 16, 256, 0, stream>>>(
        Xn, W_out, b_out, out + (size_t)t * BATCH * 5, emb_pred, W_emb, b_emb, Xn);
  }
}